// Round 1
// baseline (453.369 us; speedup 1.0000x reference)
//
#include <hip/hip_runtime.h>

#define N_NODES 100000
#define N_EDGES 1250000
#define D 64

// ---------------- degree count ----------------
__global__ void deg_kernel(const int* __restrict__ dst, float* __restrict__ deg) {
    int i = blockIdx.x * blockDim.x + threadIdx.x;
    if (i < N_EDGES) atomicAdd(&deg[dst[i]], 1.0f);
}

// ---------------- norm = rsqrt(clip(deg,1)) in-place ----------------
__global__ void norm_kernel(float* __restrict__ deg) {
    int i = blockIdx.x * blockDim.x + threadIdx.x;
    if (i < N_NODES) {
        float d = deg[i];
        d = d < 1.0f ? 1.0f : d;
        deg[i] = rsqrtf(d);
    }
}

// ---------------- edge scatter: agg[dst] += feat[src] * norm[src] ----------------
// one wave per edge, lane = feature index (D == wave size == 64)
__global__ __launch_bounds__(256) void scatter_kernel(
    const float* __restrict__ feat,
    const int* __restrict__ src,
    const int* __restrict__ dst,
    const float* __restrict__ norm,
    float* __restrict__ agg)
{
    int e = blockIdx.x * 4 + (threadIdx.x >> 6);
    int lane = threadIdx.x & 63;
    if (e < N_EDGES) {
        int s = src[e];
        int t = dst[e];
        float v = feat[(size_t)s * D + lane] * norm[s];
        atomicAdd(&agg[(size_t)t * D + lane], v);
    }
}

// ---------------- out = (agg * norm) @ W^T + bias, in-place on d_out ----------------
// block = 256 threads, 32 nodes per block. agg rows staged to LDS before
// overwrite, so in-place is safe (blocks own disjoint rows).
__global__ __launch_bounds__(256) void gemm_kernel(
    const float* __restrict__ norm,
    const float* __restrict__ weight,   // [D_OUT][D_IN] row-major
    const float* __restrict__ bias,
    float* __restrict__ io)             // in: agg, out: result
{
    __shared__ float Wl[D * (D + 1)];   // pad to 65: bank = (d+k)&31 -> 2-way (free)
    __shared__ float tile[32 * D];

    int tid = threadIdx.x;
    int n0 = blockIdx.x * 32;

    #pragma unroll
    for (int i = tid; i < D * D; i += 256) {
        int d = i >> 6, k = i & 63;
        Wl[d * (D + 1) + k] = weight[i];
    }
    #pragma unroll
    for (int i = tid; i < 32 * D; i += 256) {
        int nl = i >> 6;
        tile[i] = io[(size_t)(n0 + nl) * D + (i & 63)] * norm[n0 + nl];
    }
    __syncthreads();

    int lane = tid & 63;       // output feature d
    int w = tid >> 6;          // wave id 0..3
    float b = bias[lane];
    float acc[8];
    #pragma unroll
    for (int j = 0; j < 8; ++j) {
        int nl = w + j * 4;
        float a = b;
        #pragma unroll
        for (int k = 0; k < D; ++k)
            a += tile[nl * D + k] * Wl[lane * (D + 1) + k];  // tile read = broadcast
        acc[j] = a;
    }
    #pragma unroll
    for (int j = 0; j < 8; ++j) {
        int nl = w + j * 4;
        io[(size_t)(n0 + nl) * D + lane] = acc[j];
    }
}

extern "C" void kernel_launch(void* const* d_in, const int* in_sizes, int n_in,
                              void* d_out, int out_size, void* d_ws, size_t ws_size,
                              hipStream_t stream) {
    const float* feat   = (const float*)d_in[0];
    const int*   src    = (const int*)d_in[1];
    const int*   dst    = (const int*)d_in[2];
    const float* weight = (const float*)d_in[3];
    const float* bias   = (const float*)d_in[4];
    float* out = (float*)d_out;
    float* deg = (float*)d_ws;   // N_NODES floats; becomes norm in-place

    hipMemsetAsync(deg, 0, N_NODES * sizeof(float), stream);
    hipMemsetAsync(out, 0, (size_t)N_NODES * D * sizeof(float), stream);

    deg_kernel<<<(N_EDGES + 255) / 256, 256, 0, stream>>>(dst, deg);
    norm_kernel<<<(N_NODES + 255) / 256, 256, 0, stream>>>(deg);
    scatter_kernel<<<(N_EDGES + 3) / 4, 256, 0, stream>>>(feat, src, dst, deg, out);
    gemm_kernel<<<N_NODES / 32, 256, 0, stream>>>(deg, weight, bias, out);
}

// Round 2
// 312.453 us; speedup vs baseline: 1.4510x; 1.4510x over previous
//
#include <hip/hip_runtime.h>

#define N_NODES 100000
#define N_EDGES 1250000
#define D 64
#define NPAD 102400          // N_NODES rounded to 25*4096 for the scan
#define SCAN_BLOCKS 25       // NPAD / 4096

// ---------------- int degree histogram ----------------
__global__ __launch_bounds__(256) void hist_kernel(const int* __restrict__ dst, int* __restrict__ cnt) {
    int e = blockIdx.x * 256 + threadIdx.x;
    if (e < N_EDGES) atomicAdd(&cnt[dst[e]], 1);
}

// ---------------- scan pass 1: per-4096-block exclusive scan ----------------
__global__ __launch_bounds__(256) void scan1_kernel(const int* __restrict__ cnt,
                                                    int* __restrict__ out,
                                                    int* __restrict__ bsums) {
    __shared__ int lds[256];
    int tid = threadIdx.x;
    int base = blockIdx.x * 4096 + tid * 16;
    int v[16], run = 0;
    #pragma unroll
    for (int i = 0; i < 16; ++i) { int t = cnt[base + i]; v[i] = run; run += t; }
    lds[tid] = run;
    __syncthreads();
    int inc = run;
    for (int off = 1; off < 256; off <<= 1) {
        int y = (tid >= off) ? lds[tid - off] : 0;
        __syncthreads();
        inc += y;
        lds[tid] = inc;
        __syncthreads();
    }
    int exc = inc - run;   // exclusive prefix of this thread's chunk within block
    #pragma unroll
    for (int i = 0; i < 16; ++i) out[base + i] = exc + v[i];
    if (tid == 255) bsums[blockIdx.x] = inc;
}

// ---------------- scan pass 2: scan the 25 block sums ----------------
__global__ void scan2_kernel(int* __restrict__ bsums) {
    if (threadIdx.x == 0) {
        int s = 0;
        for (int i = 0; i < SCAN_BLOCKS; ++i) { int t = bsums[i]; bsums[i] = s; s += t; }
    }
}

// ---------------- scan pass 3: add block offsets; emit offsets, cursor, norm ----------------
__global__ __launch_bounds__(256) void scan3_kernel(const int* __restrict__ cnt,
                                                    int* __restrict__ offs,
                                                    int* __restrict__ cursor,
                                                    float* __restrict__ norm,
                                                    const int* __restrict__ bsums) {
    int i = blockIdx.x * 256 + threadIdx.x;   // < NPAD
    int b = bsums[i >> 12];
    int v = offs[i] + b;
    offs[i] = v;
    cursor[i] = v;
    if (i < N_NODES) {
        int c = cnt[i];
        norm[i] = rsqrtf((float)(c < 1 ? 1 : c));
    }
}

// ---------------- counting-sort placement: src_sorted grouped by dst ----------------
__global__ __launch_bounds__(256) void place_kernel(const int* __restrict__ src,
                                                    const int* __restrict__ dst,
                                                    int* __restrict__ cursor,
                                                    int* __restrict__ ssorted) {
    int e = blockIdx.x * 256 + threadIdx.x;
    if (e < N_EDGES) {
        int pos = atomicAdd(&cursor[dst[e]], 1);
        ssorted[pos] = src[e];
    }
}

// ---------------- gather: one wave per node, register accumulation ----------------
// h[n] = norm[n] * sum_{j in CSR(n)} feat[s_j] * norm[s_j]  -> written to d_out
__global__ __launch_bounds__(256) void gather_kernel(const float* __restrict__ feat,
                                                     const int* __restrict__ ssorted,
                                                     const int* __restrict__ offs,
                                                     const float* __restrict__ norm,
                                                     float* __restrict__ out) {
    int n = blockIdx.x * 4 + (threadIdx.x >> 6);
    int lane = threadIdx.x & 63;
    if (n >= N_NODES) return;
    int beg = offs[n], end = offs[n + 1];
    float acc = 0.f;
    int j = beg;
    for (; j + 3 < end; j += 4) {     // 4-wide ILP on the latency-bound gathers
        int s0 = ssorted[j], s1 = ssorted[j + 1], s2 = ssorted[j + 2], s3 = ssorted[j + 3];
        float f0 = feat[(size_t)s0 * D + lane];
        float f1 = feat[(size_t)s1 * D + lane];
        float f2 = feat[(size_t)s2 * D + lane];
        float f3 = feat[(size_t)s3 * D + lane];
        acc += f0 * norm[s0] + f1 * norm[s1] + f2 * norm[s2] + f3 * norm[s3];
    }
    for (; j < end; ++j) {
        int s = ssorted[j];
        acc += feat[(size_t)s * D + lane] * norm[s];
    }
    out[(size_t)n * D + lane] = acc * norm[n];
}

// ---------------- GEMM: out = h @ W^T + bias, in-place on d_out ----------------
// 64-node tile per block; 16x16 threads, 4x4 register blocking; float4 LDS reads.
#define GPAD 68   // row pad: 4-aligned for b128, (68 mod 32)=4 keeps conflicts <=2-way for our pattern
__global__ __launch_bounds__(256) void gemm64_kernel(const float* __restrict__ weight,
                                                     const float* __restrict__ bias,
                                                     float* __restrict__ io) {
    __shared__ float Ht[D * GPAD];   // Ht[k][n]
    __shared__ float Wt[D * GPAD];   // Wt[k][d]
    int tid = threadIdx.x;
    int n0 = blockIdx.x * 64;
    int c = tid & 63;        // k index for staging (coalesced global reads)
    int r4 = tid >> 6;       // 0..3

    for (int dd = r4; dd < D; dd += 4)
        Wt[c * GPAD + dd] = weight[dd * D + c];
    for (int nl = r4; nl < 64; nl += 4) {
        int n = n0 + nl;
        Ht[c * GPAD + nl] = (n < N_NODES) ? io[(size_t)n * D + c] : 0.f;
    }
    __syncthreads();

    int tx = tid & 15, ty = tid >> 4;
    float acc[4][4] = {};
    #pragma unroll 8
    for (int k = 0; k < D; ++k) {
        float4 a = *(const float4*)&Ht[k * GPAD + ty * 4];
        float4 b = *(const float4*)&Wt[k * GPAD + tx * 4];
        acc[0][0] += a.x * b.x; acc[0][1] += a.x * b.y; acc[0][2] += a.x * b.z; acc[0][3] += a.x * b.w;
        acc[1][0] += a.y * b.x; acc[1][1] += a.y * b.y; acc[1][2] += a.y * b.z; acc[1][3] += a.y * b.w;
        acc[2][0] += a.z * b.x; acc[2][1] += a.z * b.y; acc[2][2] += a.z * b.z; acc[2][3] += a.z * b.w;
        acc[3][0] += a.w * b.x; acc[3][1] += a.w * b.y; acc[3][2] += a.w * b.z; acc[3][3] += a.w * b.w;
    }

    float4 bv = *(const float4*)&bias[tx * 4];
    #pragma unroll
    for (int i = 0; i < 4; ++i) {
        int n = n0 + ty * 4 + i;
        if (n < N_NODES) {
            float4 v = make_float4(acc[i][0] + bv.x, acc[i][1] + bv.y,
                                   acc[i][2] + bv.z, acc[i][3] + bv.w);
            *(float4*)&io[(size_t)n * D + tx * 4] = v;
        }
    }
}

extern "C" void kernel_launch(void* const* d_in, const int* in_sizes, int n_in,
                              void* d_out, int out_size, void* d_ws, size_t ws_size,
                              hipStream_t stream) {
    const float* feat   = (const float*)d_in[0];
    const int*   src    = (const int*)d_in[1];
    const int*   dst    = (const int*)d_in[2];
    const float* weight = (const float*)d_in[3];
    const float* bias   = (const float*)d_in[4];
    float* out = (float*)d_out;

    // workspace layout (4-byte units)
    int* w = (int*)d_ws;
    int*   cnt     = w;                       // [NPAD]
    int*   offs    = w + NPAD;                // [NPAD]
    int*   cursor  = w + 2 * NPAD;            // [NPAD]
    int*   bsums   = w + 3 * NPAD;            // [64]
    float* norm    = (float*)(w + 3 * NPAD + 64);   // [N_NODES]
    int*   ssorted = w + 3 * NPAD + 64 + N_NODES;   // [N_EDGES]
    // total = 3*102400 + 64 + 100000 + 1250000 ints = ~6.6 MB

    hipMemsetAsync(cnt, 0, NPAD * sizeof(int), stream);

    hist_kernel <<<(N_EDGES + 255) / 256, 256, 0, stream>>>(dst, cnt);
    scan1_kernel<<<SCAN_BLOCKS, 256, 0, stream>>>(cnt, offs, bsums);
    scan2_kernel<<<1, 64, 0, stream>>>(bsums);
    scan3_kernel<<<NPAD / 256, 256, 0, stream>>>(cnt, offs, cursor, norm, bsums);
    place_kernel<<<(N_EDGES + 255) / 256, 256, 0, stream>>>(src, dst, cursor, ssorted);
    gather_kernel<<<(N_NODES + 3) / 4, 256, 0, stream>>>(feat, ssorted, offs, norm, out);
    gemm64_kernel<<<(N_NODES + 63) / 64, 256, 0, stream>>>(weight, bias, out);
}